// Round 1
// baseline (514.215 us; speedup 1.0000x reference)
//
#include <hip/hip_runtime.h>
#include <hip/hip_bf16.h>
#include <stdint.h>

#define N_NODES 50000
#define N_EDGES 800000
#define NREL    8
#define NBASES  30
#define DIM     128
#define NSLOT   9           // 8 relations + root
#define NCAT    (NSLOT*DIM) // 1152

typedef __attribute__((ext_vector_type(8))) short short8;
typedef __attribute__((ext_vector_type(4))) float floatx4;
typedef __hip_bfloat16  bf16;
typedef __hip_bfloat162 bf16x2;

// ---------------- weight prep: WcatT[n][k] (n = r*128+o, slot 8 = root), wrelT/wrootT[o][k] ----------------
__global__ void prep_weights(const float* __restrict__ basis, const float* __restrict__ comp,
                             const float* __restrict__ root, const float* __restrict__ w_rel,
                             const float* __restrict__ w_root,
                             bf16* __restrict__ WcatT, bf16* __restrict__ wrelT, bf16* __restrict__ wrootT) {
    int idx = blockIdx.x * blockDim.x + threadIdx.x;
    const int n_cat = NCAT * DIM;            // 147456
    const int n_sq  = DIM * DIM;             // 16384
    if (idx < n_cat) {
        int k = idx & 127, n = idx >> 7;
        int r = n >> 7, o = n & 127;
        float v;
        if (r < NREL) {
            v = 0.f;
            for (int b = 0; b < NBASES; ++b)
                v += comp[r * NBASES + b] * basis[(b * DIM + k) * DIM + o];
        } else {
            v = root[k * DIM + o];
        }
        WcatT[n * DIM + k] = __float2bfloat16(v);
    } else if (idx < n_cat + n_sq) {
        int t = idx - n_cat; int k = t & 127, o = t >> 7;
        wrelT[o * DIM + k] = __float2bfloat16(w_rel[k * DIM + o]);
    } else if (idx < n_cat + 2 * n_sq) {
        int t = idx - n_cat - n_sq; int k = t & 127, o = t >> 7;
        wrootT[o * DIM + k] = __float2bfloat16(w_root[k * DIM + o]);
    }
}

// ---------------- fp32 -> bf16 node features ----------------
__global__ void conv_x(const float* __restrict__ x, bf16* __restrict__ xb, int n) {
    int i = blockIdx.x * blockDim.x + threadIdx.x;
    if (i < n) xb[i] = __float2bfloat16(x[i]);
}

// ---------------- counting sort by dst ----------------
__global__ void hist_kernel(const int* __restrict__ ei, int* __restrict__ deg) {
    int e = blockIdx.x * blockDim.x + threadIdx.x;
    if (e < N_EDGES) atomicAdd(&deg[ei[N_EDGES + e]], 1);
}

__global__ void scan_kernel(const int* __restrict__ deg, int* __restrict__ segoff, int n) {
    __shared__ int buf[1024];
    __shared__ int base_s;
    int tid = threadIdx.x;
    if (tid == 0) { segoff[0] = 0; base_s = 0; }
    __syncthreads();
    for (int start = 0; start < n; start += 1024) {
        int i = start + tid;
        int v = (i < n) ? deg[i] : 0;
        buf[tid] = v;
        __syncthreads();
        for (int o = 1; o < 1024; o <<= 1) {
            int t = (tid >= o) ? buf[tid - o] : 0;
            __syncthreads();
            buf[tid] += t;
            __syncthreads();
        }
        int incl = buf[tid];
        int base = base_s;
        if (i < n) segoff[i + 1] = base + incl;
        __syncthreads();
        if (tid == 1023) base_s = base + incl;   // incl of tid 1023 == chunk total
        __syncthreads();
    }
}

__global__ void scatter_kernel(const int* __restrict__ ei, const int* __restrict__ et,
                               const float* __restrict__ en, const int* __restrict__ segoff,
                               int* __restrict__ cur, uint2* __restrict__ rec) {
    int e = blockIdx.x * blockDim.x + threadIdx.x;
    if (e < N_EDGES) {
        int d = ei[N_EDGES + e];
        int p = segoff[d] + atomicAdd(&cur[d], 1);
        unsigned src = (unsigned)ei[e];
        unsigned typ = (unsigned)et[e];
        rec[p] = make_uint2(src | (typ << 16), __float_as_uint(en[e]));
    }
}

// ---------------- MFMA GEMM: C[M,N](bf16) = A[M,128](bf16) @ BT[N,128]^T ----------------
__global__ __launch_bounds__(256) void gemm1_kernel(const bf16* __restrict__ A, const bf16* __restrict__ BT,
                                                    bf16* __restrict__ C, int M, int N) {
    __shared__ ushort As[64][136];
    __shared__ ushort Bs[64][136];
    const ushort* Au = (const ushort*)A;
    const ushort* Bu = (const ushort*)BT;
    int tm = blockIdx.x * 64, tn = blockIdx.y * 64;

    for (int c = threadIdx.x; c < 64 * 16; c += 256) {
        int row = c >> 4, seg = c & 15;
        int gr = tm + row;
        short8 av = {0, 0, 0, 0, 0, 0, 0, 0};
        if (gr < M) av = *(const short8*)(Au + gr * 128 + seg * 8);
        *(short8*)(&As[row][seg * 8]) = av;
        short8 bv = *(const short8*)(Bu + (tn + row) * 128 + seg * 8);
        *(short8*)(&Bs[row][seg * 8]) = bv;
    }
    __syncthreads();

    int wave = threadIdx.x >> 6, lane = threadIdx.x & 63;
    int q = lane >> 4, mr = lane & 15;
    floatx4 zero = {0.f, 0.f, 0.f, 0.f};
    floatx4 acc[4] = {zero, zero, zero, zero};
#pragma unroll
    for (int kt = 0; kt < 4; ++kt) {
        short8 a = *(const short8*)(&As[wave * 16 + mr][q * 8 + kt * 32]);
#pragma unroll
        for (int nt = 0; nt < 4; ++nt) {
            short8 b = *(const short8*)(&Bs[nt * 16 + mr][q * 8 + kt * 32]);
            acc[nt] = __builtin_amdgcn_mfma_f32_16x16x32_bf16(a, b, acc[nt], 0, 0, 0);
        }
    }
#pragma unroll
    for (int nt = 0; nt < 4; ++nt)
#pragma unroll
        for (int r4 = 0; r4 < 4; ++r4) {
            int row = tm + wave * 16 + q * 4 + r4;
            if (row < M) C[row * N + tn + nt * 16 + mr] = __float2bfloat16(acc[nt][r4]);
        }
}

// ---------------- layer-1 segment sum: h = seg_sum(norm*proj[src,type]) + proj[n,8] + bias1 ----------------
__global__ void seg1_kernel(const uint2* __restrict__ rec, const int* __restrict__ segoff,
                            const bf16x2* __restrict__ proj2, const float* __restrict__ bias1,
                            bf16x2* __restrict__ h2) {
    int node = blockIdx.x * 4 + (threadIdx.x >> 6);
    if (node >= N_NODES) return;
    int lane = threadIdx.x & 63;
    int s = segoff[node], e = segoff[node + 1];
    float a0 = 0.f, a1 = 0.f;
    for (int i = s; i < e; ++i) {
        uint2 r = rec[i];
        unsigned src = r.x & 0xFFFFu;
        unsigned typ = r.x >> 16;
        float norm = __uint_as_float(r.y);
        bf16x2 v = proj2[(src * NSLOT + typ) * 64u + lane];
        a0 += norm * __bfloat162float(v.x);
        a1 += norm * __bfloat162float(v.y);
    }
    bf16x2 base = proj2[((unsigned)node * NSLOT + 8u) * 64u + lane];
    a0 += __bfloat162float(base.x) + bias1[2 * lane];
    a1 += __bfloat162float(base.y) + bias1[2 * lane + 1];
    bf16x2 o;
    o.x = __float2bfloat16(a0);
    o.y = __float2bfloat16(a1);
    h2[node * 64 + lane] = o;
}

// ---------------- layer-2 segment sum: agg2 = seg_sum(h[src]) ----------------
__global__ void seg2_kernel(const uint2* __restrict__ rec, const int* __restrict__ segoff,
                            const bf16x2* __restrict__ h2, bf16x2* __restrict__ agg2) {
    int node = blockIdx.x * 4 + (threadIdx.x >> 6);
    if (node >= N_NODES) return;
    int lane = threadIdx.x & 63;
    int s = segoff[node], e = segoff[node + 1];
    float a0 = 0.f, a1 = 0.f;
    for (int i = s; i < e; ++i) {
        unsigned src = rec[i].x & 0xFFFFu;
        bf16x2 v = h2[src * 64u + lane];
        a0 += __bfloat162float(v.x);
        a1 += __bfloat162float(v.y);
    }
    bf16x2 o;
    o.x = __float2bfloat16(a0);
    o.y = __float2bfloat16(a1);
    agg2[node * 64 + lane] = o;
}

// ---------------- final GEMM: out[M,128](f32) = agg2@w_rel + h@w_root + b_rel ----------------
__global__ __launch_bounds__(256) void gemm2_kernel(const bf16* __restrict__ A1, const bf16* __restrict__ B1T,
                                                    const bf16* __restrict__ A2, const bf16* __restrict__ B2T,
                                                    const float* __restrict__ brel, float* __restrict__ out, int M) {
    __shared__ ushort As[64][136];
    __shared__ ushort Bs[64][136];
    int tm = blockIdx.x * 64, tn = blockIdx.y * 64;
    int wave = threadIdx.x >> 6, lane = threadIdx.x & 63;
    int q = lane >> 4, mr = lane & 15;
    floatx4 zero = {0.f, 0.f, 0.f, 0.f};
    floatx4 acc[4] = {zero, zero, zero, zero};

    for (int phase = 0; phase < 2; ++phase) {
        const ushort* Au = (const ushort*)(phase ? A2 : A1);
        const ushort* Bu = (const ushort*)(phase ? B2T : B1T);
        if (phase) __syncthreads();
        for (int c = threadIdx.x; c < 64 * 16; c += 256) {
            int row = c >> 4, seg = c & 15;
            int gr = tm + row;
            short8 av = {0, 0, 0, 0, 0, 0, 0, 0};
            if (gr < M) av = *(const short8*)(Au + gr * 128 + seg * 8);
            *(short8*)(&As[row][seg * 8]) = av;
            short8 bv = *(const short8*)(Bu + (tn + row) * 128 + seg * 8);
            *(short8*)(&Bs[row][seg * 8]) = bv;
        }
        __syncthreads();
#pragma unroll
        for (int kt = 0; kt < 4; ++kt) {
            short8 a = *(const short8*)(&As[wave * 16 + mr][q * 8 + kt * 32]);
#pragma unroll
            for (int nt = 0; nt < 4; ++nt) {
                short8 b = *(const short8*)(&Bs[nt * 16 + mr][q * 8 + kt * 32]);
                acc[nt] = __builtin_amdgcn_mfma_f32_16x16x32_bf16(a, b, acc[nt], 0, 0, 0);
            }
        }
    }
#pragma unroll
    for (int nt = 0; nt < 4; ++nt)
#pragma unroll
        for (int r4 = 0; r4 < 4; ++r4) {
            int row = tm + wave * 16 + q * 4 + r4;
            int col = tn + nt * 16 + mr;
            if (row < M) out[row * 128 + col] = acc[nt][r4] + brel[col];
        }
}

extern "C" void kernel_launch(void* const* d_in, const int* in_sizes, int n_in,
                              void* d_out, int out_size, void* d_ws, size_t ws_size,
                              hipStream_t stream) {
    const float* x      = (const float*)d_in[0];
    const int*   ei     = (const int*)d_in[1];
    const int*   et     = (const int*)d_in[2];
    const float* en     = (const float*)d_in[3];
    const float* basis  = (const float*)d_in[4];
    const float* comp   = (const float*)d_in[5];
    const float* root   = (const float*)d_in[6];
    const float* bias1  = (const float*)d_in[7];
    const float* w_rel  = (const float*)d_in[8];
    const float* b_rel  = (const float*)d_in[9];
    const float* w_root = (const float*)d_in[10];
    float* out = (float*)d_out;

    char* ws = (char*)d_ws;
    size_t off = 0;
    auto alloc = [&](size_t bytes) { size_t o = off; off += (bytes + 255) & ~(size_t)255; return o; };

    size_t o_deg    = alloc(N_NODES * 4);            // zeroed
    size_t o_cur    = alloc(N_NODES * 4);            // zeroed (contiguous with deg)
    size_t o_segoff = alloc((N_NODES + 1) * 4);
    size_t o_rec    = alloc((size_t)N_EDGES * 8);
    size_t o_wcat   = alloc((size_t)NCAT * DIM * 2);
    size_t o_wrel   = alloc((size_t)DIM * DIM * 2);
    size_t o_wroot  = alloc((size_t)DIM * DIM * 2);
    size_t o_xb     = alloc((size_t)N_NODES * DIM * 2);
    size_t o_proj   = alloc((size_t)N_NODES * NCAT * 2);
    size_t o_hb     = alloc((size_t)N_NODES * DIM * 2);
    size_t o_agg2   = alloc((size_t)N_NODES * DIM * 2);

    int*   deg    = (int*)(ws + o_deg);
    int*   cur    = (int*)(ws + o_cur);
    int*   segoff = (int*)(ws + o_segoff);
    uint2* rec    = (uint2*)(ws + o_rec);
    bf16*  wcat   = (bf16*)(ws + o_wcat);
    bf16*  wrelT  = (bf16*)(ws + o_wrel);
    bf16*  wrootT = (bf16*)(ws + o_wroot);
    bf16*  xb     = (bf16*)(ws + o_xb);
    bf16*  proj   = (bf16*)(ws + o_proj);
    bf16*  hb     = (bf16*)(ws + o_hb);
    bf16*  agg2   = (bf16*)(ws + o_agg2);

    // zero deg + cur (contiguous, padded sizes are 256-multiples)
    hipMemsetAsync(ws + o_deg, 0, o_segoff - o_deg, stream);

    {   // weights
        int total = NCAT * DIM + 2 * DIM * DIM;
        prep_weights<<<(total + 255) / 256, 256, 0, stream>>>(basis, comp, root, w_rel, w_root,
                                                              wcat, wrelT, wrootT);
    }
    {   // bf16 features
        int n = N_NODES * DIM;
        conv_x<<<(n + 255) / 256, 256, 0, stream>>>(x, xb, n);
    }
    // counting sort by dst
    hist_kernel<<<(N_EDGES + 255) / 256, 256, 0, stream>>>(ei, deg);
    scan_kernel<<<1, 1024, 0, stream>>>(deg, segoff, N_NODES);
    scatter_kernel<<<(N_EDGES + 255) / 256, 256, 0, stream>>>(ei, et, en, segoff, cur, rec);

    // proj[N, 9*128] = xb @ WcatT^T
    {
        dim3 grid((N_NODES + 63) / 64, NCAT / 64);
        gemm1_kernel<<<grid, 256, 0, stream>>>(xb, wcat, proj, N_NODES, NCAT);
    }
    // layer 1 segment sum -> h (bf16)
    seg1_kernel<<<(N_NODES + 3) / 4, 256, 0, stream>>>(rec, segoff, (const bf16x2*)proj, bias1, (bf16x2*)hb);
    // layer 2 segment sum -> agg2 (bf16)
    seg2_kernel<<<(N_NODES + 3) / 4, 256, 0, stream>>>(rec, segoff, (const bf16x2*)hb, (bf16x2*)agg2);
    // out = agg2 @ w_rel + h @ w_root + b_rel
    {
        dim3 grid((N_NODES + 63) / 64, DIM / 64);
        gemm2_kernel<<<grid, 256, 0, stream>>>(agg2, wrelT, hb, wrootT, b_rel, out, N_NODES);
    }
}

// Round 2
// 437.045 us; speedup vs baseline: 1.1766x; 1.1766x over previous
//
#include <hip/hip_runtime.h>
#include <hip/hip_bf16.h>
#include <stdint.h>

#define N_NODES 50000
#define N_EDGES 800000
#define NREL    8
#define NBASES  30
#define DIM     128
#define NSLOT   9           // 8 relations + root
#define NCAT    (NSLOT*DIM) // 1152
#define SCAN_NB ((N_NODES + 255) / 256)   // 196 scan blocks

typedef __attribute__((ext_vector_type(8))) short short8;
typedef __attribute__((ext_vector_type(4))) float floatx4;
typedef __hip_bfloat16  bf16;
typedef __hip_bfloat162 bf16x2;

// ---------------- weight prep: WcatT[n][k] (n = r*128+o, slot 8 = root), wrelT/wrootT[o][k] ----------------
__global__ void prep_weights(const float* __restrict__ basis, const float* __restrict__ comp,
                             const float* __restrict__ root, const float* __restrict__ w_rel,
                             const float* __restrict__ w_root,
                             bf16* __restrict__ WcatT, bf16* __restrict__ wrelT, bf16* __restrict__ wrootT) {
    int idx = blockIdx.x * blockDim.x + threadIdx.x;
    const int n_cat = NCAT * DIM;            // 147456
    const int n_sq  = DIM * DIM;             // 16384
    if (idx < n_cat) {
        int k = idx & 127, n = idx >> 7;
        int r = n >> 7, o = n & 127;
        float v;
        if (r < NREL) {
            v = 0.f;
            for (int b = 0; b < NBASES; ++b)
                v += comp[r * NBASES + b] * basis[(b * DIM + k) * DIM + o];
        } else {
            v = root[k * DIM + o];
        }
        WcatT[n * DIM + k] = __float2bfloat16(v);
    } else if (idx < n_cat + n_sq) {
        int t = idx - n_cat; int k = t & 127, o = t >> 7;
        wrelT[o * DIM + k] = __float2bfloat16(w_rel[k * DIM + o]);
    } else if (idx < n_cat + 2 * n_sq) {
        int t = idx - n_cat - n_sq; int k = t & 127, o = t >> 7;
        wrootT[o * DIM + k] = __float2bfloat16(w_root[k * DIM + o]);
    }
}

// ---------------- fp32 -> bf16 node features ----------------
__global__ void conv_x(const float* __restrict__ x, bf16* __restrict__ xb, int n) {
    int i = blockIdx.x * blockDim.x + threadIdx.x;
    if (i < n) xb[i] = __float2bfloat16(x[i]);
}

// ---------------- counting sort by dst ----------------
__global__ void hist_kernel(const int* __restrict__ ei, int* __restrict__ deg) {
    int e = blockIdx.x * blockDim.x + threadIdx.x;
    if (e < N_EDGES) atomicAdd(&deg[ei[N_EDGES + e]], 1);
}

// Phase 1: per-block inclusive scan of deg -> segoff[i+1] (local), block total -> bsum[b]
__global__ void scan_blocks(const int* __restrict__ deg, int* __restrict__ segoff,
                            int* __restrict__ bsum, int n) {
    __shared__ int buf[256];
    int tid = threadIdx.x;
    int i = blockIdx.x * 256 + tid;
    int v = (i < n) ? deg[i] : 0;
    buf[tid] = v;
    __syncthreads();
#pragma unroll
    for (int o = 1; o < 256; o <<= 1) {
        int t = (tid >= o) ? buf[tid - o] : 0;
        __syncthreads();
        buf[tid] += t;
        __syncthreads();
    }
    if (i < n) segoff[i + 1] = buf[tid];
    if (tid == 255) bsum[blockIdx.x] = buf[255];
}

// Phase 2: single small block scans the block sums into EXCLUSIVE offsets (in place)
__global__ void scan_sums(int* __restrict__ bsum, int nb) {
    __shared__ int buf[256];
    int tid = threadIdx.x;
    int v = (tid < nb) ? bsum[tid] : 0;
    buf[tid] = v;
    __syncthreads();
#pragma unroll
    for (int o = 1; o < 256; o <<= 1) {
        int t = (tid >= o) ? buf[tid - o] : 0;
        __syncthreads();
        buf[tid] += t;
        __syncthreads();
    }
    if (tid < nb) bsum[tid] = buf[tid] - v;   // exclusive
}

// Phase 3: add block offsets; set segoff[0]=0
__global__ void scan_add(int* __restrict__ segoff, const int* __restrict__ bsum, int n) {
    int i = blockIdx.x * 256 + threadIdx.x;
    if (i < n) segoff[i + 1] += bsum[blockIdx.x];
    if (i == 0) segoff[0] = 0;
}

__global__ void scatter_kernel(const int* __restrict__ ei, const int* __restrict__ et,
                               const float* __restrict__ en, const int* __restrict__ segoff,
                               int* __restrict__ cur, uint2* __restrict__ rec) {
    int e = blockIdx.x * blockDim.x + threadIdx.x;
    if (e < N_EDGES) {
        int d = ei[N_EDGES + e];
        int p = segoff[d] + atomicAdd(&cur[d], 1);
        unsigned src = (unsigned)ei[e];
        unsigned typ = (unsigned)et[e];
        rec[p] = make_uint2(src | (typ << 16), __float_as_uint(en[e]));
    }
}

// ---------------- MFMA GEMM: C[M,N](bf16) = A[M,128](bf16) @ BT[N,128]^T ----------------
__global__ __launch_bounds__(256) void gemm1_kernel(const bf16* __restrict__ A, const bf16* __restrict__ BT,
                                                    bf16* __restrict__ C, int M, int N) {
    __shared__ ushort As[64][136];
    __shared__ ushort Bs[64][136];
    const ushort* Au = (const ushort*)A;
    const ushort* Bu = (const ushort*)BT;
    int tm = blockIdx.x * 64, tn = blockIdx.y * 64;

    for (int c = threadIdx.x; c < 64 * 16; c += 256) {
        int row = c >> 4, seg = c & 15;
        int gr = tm + row;
        short8 av = {0, 0, 0, 0, 0, 0, 0, 0};
        if (gr < M) av = *(const short8*)(Au + gr * 128 + seg * 8);
        *(short8*)(&As[row][seg * 8]) = av;
        short8 bv = *(const short8*)(Bu + (tn + row) * 128 + seg * 8);
        *(short8*)(&Bs[row][seg * 8]) = bv;
    }
    __syncthreads();

    int wave = threadIdx.x >> 6, lane = threadIdx.x & 63;
    int q = lane >> 4, mr = lane & 15;
    floatx4 zero = {0.f, 0.f, 0.f, 0.f};
    floatx4 acc[4] = {zero, zero, zero, zero};
#pragma unroll
    for (int kt = 0; kt < 4; ++kt) {
        short8 a = *(const short8*)(&As[wave * 16 + mr][q * 8 + kt * 32]);
#pragma unroll
        for (int nt = 0; nt < 4; ++nt) {
            short8 b = *(const short8*)(&Bs[nt * 16 + mr][q * 8 + kt * 32]);
            acc[nt] = __builtin_amdgcn_mfma_f32_16x16x32_bf16(a, b, acc[nt], 0, 0, 0);
        }
    }
#pragma unroll
    for (int nt = 0; nt < 4; ++nt)
#pragma unroll
        for (int r4 = 0; r4 < 4; ++r4) {
            int row = tm + wave * 16 + q * 4 + r4;
            if (row < M) C[row * N + tn + nt * 16 + mr] = __float2bfloat16(acc[nt][r4]);
        }
}

// ---------------- layer-1 segment sum: h = seg_sum(norm*proj[src,type]) + proj[n,8] + bias1 ----------------
__global__ void seg1_kernel(const uint2* __restrict__ rec, const int* __restrict__ segoff,
                            const bf16x2* __restrict__ proj2, const float* __restrict__ bias1,
                            bf16x2* __restrict__ h2) {
    int node = blockIdx.x * 4 + (threadIdx.x >> 6);
    if (node >= N_NODES) return;
    int lane = threadIdx.x & 63;
    int s = segoff[node], e = segoff[node + 1];
    float a0 = 0.f, a1 = 0.f;
    for (int i = s; i < e; ++i) {
        uint2 r = rec[i];
        unsigned src = r.x & 0xFFFFu;
        unsigned typ = r.x >> 16;
        float norm = __uint_as_float(r.y);
        bf16x2 v = proj2[(src * NSLOT + typ) * 64u + lane];
        a0 += norm * __bfloat162float(v.x);
        a1 += norm * __bfloat162float(v.y);
    }
    bf16x2 base = proj2[((unsigned)node * NSLOT + 8u) * 64u + lane];
    a0 += __bfloat162float(base.x) + bias1[2 * lane];
    a1 += __bfloat162float(base.y) + bias1[2 * lane + 1];
    bf16x2 o;
    o.x = __float2bfloat16(a0);
    o.y = __float2bfloat16(a1);
    h2[node * 64 + lane] = o;
}

// ---------------- layer-2 segment sum: agg2 = seg_sum(h[src]) ----------------
__global__ void seg2_kernel(const uint2* __restrict__ rec, const int* __restrict__ segoff,
                            const bf16x2* __restrict__ h2, bf16x2* __restrict__ agg2) {
    int node = blockIdx.x * 4 + (threadIdx.x >> 6);
    if (node >= N_NODES) return;
    int lane = threadIdx.x & 63;
    int s = segoff[node], e = segoff[node + 1];
    float a0 = 0.f, a1 = 0.f;
    for (int i = s; i < e; ++i) {
        unsigned src = rec[i].x & 0xFFFFu;
        bf16x2 v = h2[src * 64u + lane];
        a0 += __bfloat162float(v.x);
        a1 += __bfloat162float(v.y);
    }
    bf16x2 o;
    o.x = __float2bfloat16(a0);
    o.y = __float2bfloat16(a1);
    agg2[node * 64 + lane] = o;
}

// ---------------- final GEMM: out[M,128](f32) = agg2@w_rel + h@w_root + b_rel ----------------
__global__ __launch_bounds__(256) void gemm2_kernel(const bf16* __restrict__ A1, const bf16* __restrict__ B1T,
                                                    const bf16* __restrict__ A2, const bf16* __restrict__ B2T,
                                                    const float* __restrict__ brel, float* __restrict__ out, int M) {
    __shared__ ushort As[64][136];
    __shared__ ushort Bs[64][136];
    int tm = blockIdx.x * 64, tn = blockIdx.y * 64;
    int wave = threadIdx.x >> 6, lane = threadIdx.x & 63;
    int q = lane >> 4, mr = lane & 15;
    floatx4 zero = {0.f, 0.f, 0.f, 0.f};
    floatx4 acc[4] = {zero, zero, zero, zero};

    for (int phase = 0; phase < 2; ++phase) {
        const ushort* Au = (const ushort*)(phase ? A2 : A1);
        const ushort* Bu = (const ushort*)(phase ? B2T : B1T);
        if (phase) __syncthreads();
        for (int c = threadIdx.x; c < 64 * 16; c += 256) {
            int row = c >> 4, seg = c & 15;
            int gr = tm + row;
            short8 av = {0, 0, 0, 0, 0, 0, 0, 0};
            if (gr < M) av = *(const short8*)(Au + gr * 128 + seg * 8);
            *(short8*)(&As[row][seg * 8]) = av;
            short8 bv = *(const short8*)(Bu + (tn + row) * 128 + seg * 8);
            *(short8*)(&Bs[row][seg * 8]) = bv;
        }
        __syncthreads();
#pragma unroll
        for (int kt = 0; kt < 4; ++kt) {
            short8 a = *(const short8*)(&As[wave * 16 + mr][q * 8 + kt * 32]);
#pragma unroll
            for (int nt = 0; nt < 4; ++nt) {
                short8 b = *(const short8*)(&Bs[nt * 16 + mr][q * 8 + kt * 32]);
                acc[nt] = __builtin_amdgcn_mfma_f32_16x16x32_bf16(a, b, acc[nt], 0, 0, 0);
            }
        }
    }
#pragma unroll
    for (int nt = 0; nt < 4; ++nt)
#pragma unroll
        for (int r4 = 0; r4 < 4; ++r4) {
            int row = tm + wave * 16 + q * 4 + r4;
            int col = tn + nt * 16 + mr;
            if (row < M) out[row * 128 + col] = acc[nt][r4] + brel[col];
        }
}

extern "C" void kernel_launch(void* const* d_in, const int* in_sizes, int n_in,
                              void* d_out, int out_size, void* d_ws, size_t ws_size,
                              hipStream_t stream) {
    const float* x      = (const float*)d_in[0];
    const int*   ei     = (const int*)d_in[1];
    const int*   et     = (const int*)d_in[2];
    const float* en     = (const float*)d_in[3];
    const float* basis  = (const float*)d_in[4];
    const float* comp   = (const float*)d_in[5];
    const float* root   = (const float*)d_in[6];
    const float* bias1  = (const float*)d_in[7];
    const float* w_rel  = (const float*)d_in[8];
    const float* b_rel  = (const float*)d_in[9];
    const float* w_root = (const float*)d_in[10];
    float* out = (float*)d_out;

    char* ws = (char*)d_ws;
    size_t off = 0;
    auto alloc = [&](size_t bytes) { size_t o = off; off += (bytes + 255) & ~(size_t)255; return o; };

    size_t o_deg    = alloc(N_NODES * 4);            // zeroed
    size_t o_cur    = alloc(N_NODES * 4);            // zeroed (contiguous with deg)
    size_t o_segoff = alloc((N_NODES + 1) * 4);
    size_t o_bsum   = alloc(SCAN_NB * 4);
    size_t o_rec    = alloc((size_t)N_EDGES * 8);
    size_t o_wcat   = alloc((size_t)NCAT * DIM * 2);
    size_t o_wrel   = alloc((size_t)DIM * DIM * 2);
    size_t o_wroot  = alloc((size_t)DIM * DIM * 2);
    size_t o_xb     = alloc((size_t)N_NODES * DIM * 2);
    size_t o_proj   = alloc((size_t)N_NODES * NCAT * 2);
    size_t o_hb     = alloc((size_t)N_NODES * DIM * 2);
    size_t o_agg2   = alloc((size_t)N_NODES * DIM * 2);

    int*   deg    = (int*)(ws + o_deg);
    int*   cur    = (int*)(ws + o_cur);
    int*   segoff = (int*)(ws + o_segoff);
    int*   bsum   = (int*)(ws + o_bsum);
    uint2* rec    = (uint2*)(ws + o_rec);
    bf16*  wcat   = (bf16*)(ws + o_wcat);
    bf16*  wrelT  = (bf16*)(ws + o_wrel);
    bf16*  wrootT = (bf16*)(ws + o_wroot);
    bf16*  xb     = (bf16*)(ws + o_xb);
    bf16*  proj   = (bf16*)(ws + o_proj);
    bf16*  hb     = (bf16*)(ws + o_hb);
    bf16*  agg2   = (bf16*)(ws + o_agg2);

    // zero deg + cur (contiguous, padded sizes are 256-multiples)
    hipMemsetAsync(ws + o_deg, 0, o_segoff - o_deg, stream);

    {   // weights
        int total = NCAT * DIM + 2 * DIM * DIM;
        prep_weights<<<(total + 255) / 256, 256, 0, stream>>>(basis, comp, root, w_rel, w_root,
                                                              wcat, wrelT, wrootT);
    }
    {   // bf16 features
        int n = N_NODES * DIM;
        conv_x<<<(n + 255) / 256, 256, 0, stream>>>(x, xb, n);
    }
    // counting sort by dst
    hist_kernel<<<(N_EDGES + 255) / 256, 256, 0, stream>>>(ei, deg);
    scan_blocks<<<SCAN_NB, 256, 0, stream>>>(deg, segoff, bsum, N_NODES);
    scan_sums<<<1, 256, 0, stream>>>(bsum, SCAN_NB);
    scan_add<<<SCAN_NB, 256, 0, stream>>>(segoff, bsum, N_NODES);
    scatter_kernel<<<(N_EDGES + 255) / 256, 256, 0, stream>>>(ei, et, en, segoff, cur, rec);

    // proj[N, 9*128] = xb @ WcatT^T
    {
        dim3 grid((N_NODES + 63) / 64, NCAT / 64);
        gemm1_kernel<<<grid, 256, 0, stream>>>(xb, wcat, proj, N_NODES, NCAT);
    }
    // layer 1 segment sum -> h (bf16)
    seg1_kernel<<<(N_NODES + 3) / 4, 256, 0, stream>>>(rec, segoff, (const bf16x2*)proj, bias1, (bf16x2*)hb);
    // layer 2 segment sum -> agg2 (bf16)
    seg2_kernel<<<(N_NODES + 3) / 4, 256, 0, stream>>>(rec, segoff, (const bf16x2*)hb, (bf16x2*)agg2);
    // out = agg2 @ w_rel + h @ w_root + b_rel
    {
        dim3 grid((N_NODES + 63) / 64, DIM / 64);
        gemm2_kernel<<<grid, 256, 0, stream>>>(agg2, wrelT, hb, wrootT, b_rel, out, N_NODES);
    }
}